// Round 12
// baseline (185.956 us; speedup 1.0000x reference)
//
#include <hip/hip_runtime.h>
#include <hip/hip_bf16.h>

// Problem constants
#define B_  16
#define S1_ 128
#define S2_ 256
#define H_  256
#define HM_ 512
#define QB  4    // q-rows per attn block-job
#define ESTR 520 // proj LDS row stride in halves

typedef _Float16 hf2 __attribute__((ext_vector_type(2)));
typedef _Float16 hf4 __attribute__((ext_vector_type(4)));
typedef _Float16 hf8 __attribute__((ext_vector_type(8)));
typedef float    f32x4 __attribute__((ext_vector_type(4)));

static __device__ inline hf2 u2h(unsigned u) {
    union { unsigned u; hf2 h; } x; x.u = u; return x.h;
}

static __device__ inline float dot2(hf2 a, hf2 b, float c) {
#if __has_builtin(__builtin_amdgcn_fdot2)
    return __builtin_amdgcn_fdot2(a, b, c, false);
#else
    asm("v_dot2_f32_f16 %0, %1, %2, %0" : "+v"(c) : "v"(a), "v"(b));
    return c;
#endif
}

struct AttnS {
    _Float16 qp_h[QB][HM_];     // 4 KB
    _Float16 w2_h[HM_];         // 1 KB
    float    Ap[2][QB][S2_];    // 8 KB
    float4   opart[8][QB][64];  // 32 KB
    float    rA_s[QB];
    float    qm_s[QB];
    float    km_s[S2_];
};
union SMemU {
    AttnS    a;
    _Float16 es[16 * ESTR];     // 16.6 KB proj C/X tile
};

// Manual grid barrier: every block signals (release), all wait for `target`.
// Requires all blocks co-resident: grid 512, LDS 46.6KB -> 3 blocks/CU
// (capacity 768), verified co-resident by r11's cooperative run.
static __device__ inline void grid_barrier(unsigned* flag, unsigned target) {
    __syncthreads();                       // block stores done (drains vmcnt)
    if (threadIdx.x == 0) {
        __threadfence();                   // device-scope release (L2 wb)
        __hip_atomic_fetch_add(flag, 1u, __ATOMIC_RELEASE,
                               __HIP_MEMORY_SCOPE_AGENT);
        while (__hip_atomic_load(flag, __ATOMIC_ACQUIRE,
                                 __HIP_MEMORY_SCOPE_AGENT) < target)
            __builtin_amdgcn_s_sleep(2);
    }
    __syncthreads();
}

// ---------------------------------------------------------------------------
// fused: ONE dispatch, 512 blocks x 512 threads, manual barriers.
//  phase 0: WB = frag-order fp16 repack of W1 (64 jobs/block)
//  phase 1: proj (blocks 0..383): QPh / KPTh via MFMA, coalesced epilogue
//  phase 2: attn (all 512 blocks) — logic identical to r10/r11
// ---------------------------------------------------------------------------
__global__ __launch_bounds__(512, 4) void fused_kernel(
    const float* __restrict__ query,
    const float* __restrict__ key,
    const float* __restrict__ value,
    const float* __restrict__ q_mask,
    const float* __restrict__ k_mask,
    const float* __restrict__ W1,
    const float* __restrict__ b1,
    const float* __restrict__ W2,
    const float* __restrict__ b2,
    float* __restrict__ out,
    _Float16* __restrict__ QPh,    // [2048][512]
    _Float16* __restrict__ KPTh,   // [16][64][256][8]
    _Float16* __restrict__ WB,     // frag-order W
    unsigned* __restrict__ flags)  // [2], zeroed by hipMemsetAsync per call
{
    __shared__ SMemU sm;

    const int t   = threadIdx.x;
    const int blk = blockIdx.x;

    // ---------------- phase 0: cvtWB (spread over all blocks) ----------------
    if (t < 64) {
        const int idx  = blk * 64 + t;            // 0..32767
        const int lane = idx & 63;
        const int nblk = (idx >> 6) & 31;
        const int kblk = idx >> 11;               // 0..15
        const int n    = nblk * 16 + (lane & 15);
        const int k0   = kblk * 32 + (lane >> 4) * 8;
        hf8 v;
#pragma unroll
        for (int j = 0; j < 8; ++j)
            v[j] = (_Float16)W1[(size_t)(k0 + j) * HM_ + n];
        *(hf8*)(WB + (size_t)idx * 8) = v;
    }
    grid_barrier(&flags[0], 512);

    // ---------------- phase 1: proj (blocks 0..383) ----------------
    if (blk < 384) {
        const bool modeK = blk >= 128;
        const int m0  = (modeK ? blk - 128 : blk) * 16;
        const float* X = modeK ? key : query;
        const int kb  = modeK ? 8 : 0;

        // stage X tile (16 rows x 256 k), fp32 -> fp16
        {
            const int row = t >> 5, c8 = (t & 31) * 8;
            const float* xs = X + (size_t)(m0 + row) * H_ + c8;
            float4 xa = *(const float4*)xs;
            float4 xb = *(const float4*)(xs + 4);
            hf8 xh = { (_Float16)xa.x, (_Float16)xa.y, (_Float16)xa.z, (_Float16)xa.w,
                       (_Float16)xb.x, (_Float16)xb.y, (_Float16)xb.z, (_Float16)xb.w };
            *(hf8*)&sm.es[row * ESTR + c8] = xh;
        }
        __syncthreads();

        const int lane = t & 63, w = t >> 6;
        const int fr = lane & 15;
        const int fk = (lane >> 4) * 8;

        f32x4 acc[4] = {};
#pragma unroll
        for (int s = 0; s < 8; ++s) {
            hf8 a = *(const hf8*)&sm.es[fr * ESTR + s * 32 + fk];
            const _Float16* bp =
                WB + ((((size_t)(kb + s) * 32 + w * 4) * 64) + lane) * 8;
#pragma unroll
            for (int nf = 0; nf < 4; ++nf) {
                hf8 bv = *(const hf8*)(bp + (size_t)nf * 64 * 8);
                acc[nf] = __builtin_amdgcn_mfma_f32_16x16x32_f16(a, bv, acc[nf], 0, 0, 0);
            }
        }

        __syncthreads();   // X reads done; reuse es as C tile

        // scatter acc -> es[mlocal][n] (fp16, bias folded for K mode)
#pragma unroll
        for (int nf = 0; nf < 4; ++nf) {
            const int n = w * 64 + nf * 16 + fr;
            const float bv = modeK ? b1[n] : 0.f;
#pragma unroll
            for (int r = 0; r < 4; ++r) {
                const int ml = (lane >> 4) * 4 + r;
                sm.es[ml * ESTR + n] = (_Float16)(acc[nf][r] + bv);
            }
        }
        __syncthreads();

        if (!modeK) {
            // QPh: 16 rows x 64 uint4 = 1024, 2 per thread
#pragma unroll
            for (int p = 0; p < 2; ++p) {
                const int idx = t + p * 512;
                const int row = idx >> 6, c8 = (idx & 63) * 8;
                *(uint4*)(QPh + (size_t)(m0 + row) * HM_ + c8) =
                    *(const uint4*)&sm.es[row * ESTR + c8];
            }
        } else {
            const int bb = m0 >> 8, kbase = m0 & 255;
#pragma unroll
            for (int p = 0; p < 2; ++p) {
                const int idx = t + p * 512;
                const int h8 = idx >> 4, kl = idx & 15;
                *(uint4*)(KPTh + (((size_t)bb * 64 + h8) * 256 + kbase + kl) * 8) =
                    *(const uint4*)&sm.es[kl * ESTR + h8 * 8];
            }
        }
    }
    grid_barrier(&flags[1], 512);

    // ---------------- phase 2: attn (all 512 blocks) ----------------
    {
        const int k  = t & 255;
        const int hb = t >> 8;

        // XCD-aware swizzle
        const int orig = blk;                       // 0..511
        const int wg   = (orig & 7) * 64 + (orig >> 3);
        const int q0   = (wg & 31) * QB;
        const int b    = wg >> 5;

        // stage qp (fp16), w2 (cvt), masks
        if (t < 256) {
            const uint4* src = (const uint4*)(QPh + (size_t)(b * S1_ + q0) * HM_);
            ((uint4*)&sm.a.qp_h[0][0])[t] = src[t];
            sm.a.km_s[t] = k_mask[b * S2_ + t];
        } else if (t < 256 + 128) {
            const int i = t - 256;
            float4 wvv = ((const float4*)W2)[i];
            hf4 hv = { (_Float16)wvv.x, (_Float16)wvv.y,
                       (_Float16)wvv.z, (_Float16)wvv.w };
            *(hf4*)&sm.a.w2_h[i * 4] = hv;
        } else if (t < 256 + 128 + QB) {
            const int i = t - (256 + 128);
            sm.a.qm_s[i] = q_mask[b * S1_ + q0 + i];
        }
        __syncthreads();

        // phase 2a: score partials (32 chunks of 8 h)
        float accs[QB] = {0.f, 0.f, 0.f, 0.f};
        const uint4* kp8 = (const uint4*)KPTh + ((size_t)b * 64 + hb * 32) * S2_ + k;

        for (int c = 0; c < 32; ++c) {
            uint4 kvu = kp8[(size_t)c * S2_];
            const int hoff = hb * (HM_ / 2) + c * 8;
            uint4 w4u = *(const uint4*)&sm.a.w2_h[hoff];
            hf2 kv0 = u2h(kvu.x), kv1 = u2h(kvu.y), kv2 = u2h(kvu.z), kv3 = u2h(kvu.w);
            hf2 wv0 = u2h(w4u.x), wv1 = u2h(w4u.y), wv2 = u2h(w4u.z), wv3 = u2h(w4u.w);
            const hf2 zero = (hf2)(_Float16)0;
#pragma unroll
            for (int q = 0; q < QB; ++q) {
                uint4 qvu = *(const uint4*)&sm.a.qp_h[q][hoff];
                hf2 s;
                s = __builtin_elementwise_max(u2h(qvu.x) + kv0, zero);
                accs[q] = dot2(s, wv0, accs[q]);
                s = __builtin_elementwise_max(u2h(qvu.y) + kv1, zero);
                accs[q] = dot2(s, wv1, accs[q]);
                s = __builtin_elementwise_max(u2h(qvu.z) + kv2, zero);
                accs[q] = dot2(s, wv2, accs[q]);
                s = __builtin_elementwise_max(u2h(qvu.w) + kv3, zero);
                accs[q] = dot2(s, wv3, accs[q]);
            }
        }
#pragma unroll
        for (int q = 0; q < QB; ++q) sm.a.Ap[hb][q][k] = accs[q];
        __syncthreads();

        // phase 2b: combine halves, mask, exp
        {
            const float b2v = b2[0];
#pragma unroll
            for (int i = 0; i < 2; ++i) {
                const int idx = t + i * 512;
                const int q = idx >> 8, kk = idx & 255;
                float sc = sm.a.Ap[0][q][kk] + sm.a.Ap[1][q][kk] + b2v;
                sm.a.Ap[0][q][kk] =
                    (sm.a.qm_s[q] * sm.a.km_s[kk] == 0.f) ? 0.f : __expf(sc);
            }
        }
        __syncthreads();

        // row sums
        if (t < QB * 64) {
            const int q = t >> 6, lane = t & 63;
            float p = sm.a.Ap[0][q][lane] + sm.a.Ap[0][q][lane + 64] +
                      sm.a.Ap[0][q][lane + 128] + sm.a.Ap[0][q][lane + 192];
#pragma unroll
            for (int m = 32; m >= 1; m >>= 1) p += __shfl_xor(p, m, 64);
            if (lane == 0) sm.a.rA_s[q] = 1.0f / fmaxf(p, 2e-15f);
        }
        __syncthreads();

        // PV: wave w owns value rows [w*32, w*32+32) for all 4 q
        {
            const int w = t >> 6, lane = t & 63;
            const float4* vb = (const float4*)(value + (size_t)b * S2_ * H_)
                               + (size_t)(w * 32) * (H_ / 4) + lane;
            float4 o[QB];
#pragma unroll
            for (int q = 0; q < QB; ++q) o[q] = make_float4(0.f, 0.f, 0.f, 0.f);
#pragma unroll 4
            for (int kk = 0; kk < 32; ++kk) {
                float4 v = vb[(size_t)kk * (H_ / 4)];
#pragma unroll
                for (int q = 0; q < QB; ++q) {
                    float a = sm.a.Ap[0][q][w * 32 + kk];
                    o[q].x = fmaf(a, v.x, o[q].x); o[q].y = fmaf(a, v.y, o[q].y);
                    o[q].z = fmaf(a, v.z, o[q].z); o[q].w = fmaf(a, v.w, o[q].w);
                }
            }
#pragma unroll
            for (int q = 0; q < QB; ++q) sm.a.opart[w][q][lane] = o[q];
        }
        __syncthreads();

        // combine 8 partials, normalize, store
        if (t < QB * 64) {
            const int q = t >> 6, lane = t & 63;
            float4 s = make_float4(0.f, 0.f, 0.f, 0.f);
#pragma unroll
            for (int w = 0; w < 8; ++w) {
                float4 p = sm.a.opart[w][q][lane];
                s.x += p.x; s.y += p.y; s.z += p.z; s.w += p.w;
            }
            const float r = sm.a.rA_s[q];
            s.x *= r; s.y *= r; s.z *= r; s.w *= r;
            *(float4*)(out + (size_t)(b * S1_ + q0 + q) * H_ + lane * 4) = s;
        }
    }
}

extern "C" void kernel_launch(void* const* d_in, const int* in_sizes, int n_in,
                              void* d_out, int out_size, void* d_ws, size_t ws_size,
                              hipStream_t stream) {
    const float* query  = (const float*)d_in[0];  // [16,128,256]
    const float* key    = (const float*)d_in[1];  // [16,256,256]
    const float* value  = (const float*)d_in[2];  // [16,256,256]
    const float* q_mask = (const float*)d_in[3];  // [16,128]
    const float* k_mask = (const float*)d_in[4];  // [16,256]
    const float* W1     = (const float*)d_in[5];  // [512,512]
    const float* b1     = (const float*)d_in[6];  // [512]
    const float* W2     = (const float*)d_in[7];  // [512,1]
    const float* b2     = (const float*)d_in[8];  // [1]
    float*       out    = (float*)d_out;

    _Float16* QPh  = (_Float16*)d_ws;                  // [2048][512]      2 MB
    _Float16* KPTh = QPh  + (size_t)B_ * S1_ * HM_;    // [16][64][256][8] 4 MB
    _Float16* WB   = KPTh + (size_t)B_ * S2_ * HM_;    // frag-order W   0.5 MB
    unsigned* flags = (unsigned*)(WB + (size_t)HM_ * HM_);  // 2 x u32

    // zero the barrier flags each call (async, graph-capturable)
    hipMemsetAsync(flags, 0, 2 * sizeof(unsigned), stream);

    fused_kernel<<<512, 512, 0, stream>>>(
        query, key, value, q_mask, k_mask, W1, b1, W2, b2,
        out, QPh, KPTh, WB, flags);
}

// Round 13
// 180.132 us; speedup vs baseline: 1.0323x; 1.0323x over previous
//
#include <hip/hip_runtime.h>
#include <hip/hip_bf16.h>

// Problem constants
#define B_  16
#define S1_ 128
#define S2_ 256
#define H_  256
#define HM_ 512
#define QB  4    // q-rows per attn block-job
#define ESTR 520 // proj LDS row stride in halves
#define NBLK 512

typedef _Float16 hf2 __attribute__((ext_vector_type(2)));
typedef _Float16 hf4 __attribute__((ext_vector_type(4)));
typedef _Float16 hf8 __attribute__((ext_vector_type(8)));
typedef float    f32x4 __attribute__((ext_vector_type(4)));

static __device__ inline hf2 u2h(unsigned u) {
    union { unsigned u; hf2 h; } x; x.u = u; return x.h;
}

static __device__ inline float dot2(hf2 a, hf2 b, float c) {
#if __has_builtin(__builtin_amdgcn_fdot2)
    return __builtin_amdgcn_fdot2(a, b, c, false);
#else
    asm("v_dot2_f32_f16 %0, %1, %2, %0" : "+v"(c) : "v"(a), "v"(b));
    return c;
#endif
}

struct AttnS {
    _Float16 qp_h[QB][HM_];     // 4 KB
    _Float16 w2_h[HM_];         // 1 KB
    float    Ap[2][QB][S2_];    // 8 KB
    float4   opart[8][QB][64];  // 32 KB
    float    rA_s[QB];
    float    qm_s[QB];
    float    km_s[S2_];
};
union SMemU {
    AttnS    a;
    _Float16 es[16 * ESTR];     // 16.6 KB proj C/X tile
};

// Tree grid barrier: per-block arrival flags (parallel stores, no RMW),
// block 0 scans with 512 threads, one read-only 'go' broadcast.
// Deadlock-safe: grid 512, LDS 46.6KB + VGPR 40 -> >=2 blocks/CU co-resident
// (validated by r11's cooperative launch at identical footprint).
static __device__ inline void tree_barrier(unsigned* arr, unsigned* go,
                                           int blk, unsigned gen) {
    __syncthreads();
    const int t = threadIdx.x;
    if (t == 0)
        __hip_atomic_store(&arr[blk], gen, __ATOMIC_RELEASE,
                           __HIP_MEMORY_SCOPE_AGENT);
    if (blk == 0) {
        while (__hip_atomic_load(&arr[t], __ATOMIC_ACQUIRE,
                                 __HIP_MEMORY_SCOPE_AGENT) < gen)
            __builtin_amdgcn_s_sleep(1);
        __syncthreads();
        if (t == 0)
            __hip_atomic_store(go, gen, __ATOMIC_RELEASE,
                               __HIP_MEMORY_SCOPE_AGENT);
    }
    if (t == 0)
        while (__hip_atomic_load(go, __ATOMIC_ACQUIRE,
                                 __HIP_MEMORY_SCOPE_AGENT) < gen)
            __builtin_amdgcn_s_sleep(1);
    __syncthreads();
}

// ---------------------------------------------------------------------------
// fused: ONE dispatch, 512 blocks x 512 threads, tree barriers.
//  phase 0: WB = frag-order fp16 repack of W1
//  phase 1: proj (blocks 0..383): QPh / KPTh via MFMA, coalesced epilogue
//  phase 2: attn (all blocks) + q-mask uniform skip + kp prefetch
// ---------------------------------------------------------------------------
__global__ __launch_bounds__(512, 4) void fused_kernel(
    const float* __restrict__ query,
    const float* __restrict__ key,
    const float* __restrict__ value,
    const float* __restrict__ q_mask,
    const float* __restrict__ k_mask,
    const float* __restrict__ W1,
    const float* __restrict__ b1,
    const float* __restrict__ W2,
    const float* __restrict__ b2,
    float* __restrict__ out,
    _Float16* __restrict__ QPh,    // [2048][512]
    _Float16* __restrict__ KPTh,   // [16][64][256][8]
    _Float16* __restrict__ WB,     // frag-order W
    unsigned* __restrict__ arr,    // [512] arrival flags (zeroed per call)
    unsigned* __restrict__ go)     // [1]  broadcast flag (zeroed per call)
{
    __shared__ SMemU sm;

    const int t   = threadIdx.x;
    const int blk = blockIdx.x;

    // ---------------- phase 0: cvtWB ----------------
    if (t < 64) {
        const int idx  = blk * 64 + t;            // 0..32767
        const int lane = idx & 63;
        const int nblk = (idx >> 6) & 31;
        const int kblk = idx >> 11;               // 0..15
        const int n    = nblk * 16 + (lane & 15);
        const int k0   = kblk * 32 + (lane >> 4) * 8;
        hf8 v;
#pragma unroll
        for (int j = 0; j < 8; ++j)
            v[j] = (_Float16)W1[(size_t)(k0 + j) * HM_ + n];
        *(hf8*)(WB + (size_t)idx * 8) = v;
    }
    tree_barrier(arr, go, blk, 1u);

    // ---------------- phase 1: proj (blocks 0..383) ----------------
    if (blk < 384) {
        const bool modeK = blk >= 128;
        const int m0  = (modeK ? blk - 128 : blk) * 16;
        const float* X = modeK ? key : query;
        const int kb  = modeK ? 8 : 0;

        {
            const int row = t >> 5, c8 = (t & 31) * 8;
            const float* xs = X + (size_t)(m0 + row) * H_ + c8;
            float4 xa = *(const float4*)xs;
            float4 xb = *(const float4*)(xs + 4);
            hf8 xh = { (_Float16)xa.x, (_Float16)xa.y, (_Float16)xa.z, (_Float16)xa.w,
                       (_Float16)xb.x, (_Float16)xb.y, (_Float16)xb.z, (_Float16)xb.w };
            *(hf8*)&sm.es[row * ESTR + c8] = xh;
        }
        __syncthreads();

        const int lane = t & 63, w = t >> 6;
        const int fr = lane & 15;
        const int fk = (lane >> 4) * 8;

        f32x4 acc[4] = {};
#pragma unroll
        for (int s = 0; s < 8; ++s) {
            hf8 a = *(const hf8*)&sm.es[fr * ESTR + s * 32 + fk];
            const _Float16* bp =
                WB + ((((size_t)(kb + s) * 32 + w * 4) * 64) + lane) * 8;
#pragma unroll
            for (int nf = 0; nf < 4; ++nf) {
                hf8 bv = *(const hf8*)(bp + (size_t)nf * 64 * 8);
                acc[nf] = __builtin_amdgcn_mfma_f32_16x16x32_f16(a, bv, acc[nf], 0, 0, 0);
            }
        }

        __syncthreads();   // X reads done; reuse es as C tile

#pragma unroll
        for (int nf = 0; nf < 4; ++nf) {
            const int n = w * 64 + nf * 16 + fr;
            const float bv = modeK ? b1[n] : 0.f;
#pragma unroll
            for (int r = 0; r < 4; ++r) {
                const int ml = (lane >> 4) * 4 + r;
                sm.es[ml * ESTR + n] = (_Float16)(acc[nf][r] + bv);
            }
        }
        __syncthreads();

        if (!modeK) {
#pragma unroll
            for (int p = 0; p < 2; ++p) {
                const int idx = t + p * 512;
                const int row = idx >> 6, c8 = (idx & 63) * 8;
                *(uint4*)(QPh + (size_t)(m0 + row) * HM_ + c8) =
                    *(const uint4*)&sm.es[row * ESTR + c8];
            }
        } else {
            const int bb = m0 >> 8, kbase = m0 & 255;
#pragma unroll
            for (int p = 0; p < 2; ++p) {
                const int idx = t + p * 512;
                const int h8 = idx >> 4, kl = idx & 15;
                *(uint4*)(KPTh + (((size_t)bb * 64 + h8) * 256 + kbase + kl) * 8) =
                    *(const uint4*)&sm.es[kl * ESTR + h8 * 8];
            }
        }
    }
    tree_barrier(arr, go, blk, 2u);

    // ---------------- phase 2: attn (all 512 blocks) ----------------
    {
        const int k  = t & 255;
        const int hb = t >> 8;

        const int orig = blk;                       // 0..511
        const int wg   = (orig & 7) * 64 + (orig >> 3);
        const int q0   = (wg & 31) * QB;
        const int b    = wg >> 5;

        if (t < 256) {
            const uint4* src = (const uint4*)(QPh + (size_t)(b * S1_ + q0) * HM_);
            ((uint4*)&sm.a.qp_h[0][0])[t] = src[t];
            sm.a.km_s[t] = k_mask[b * S2_ + t];
        } else if (t < 256 + 128) {
            const int i = t - 256;
            float4 wvv = ((const float4*)W2)[i];
            hf4 hv = { (_Float16)wvv.x, (_Float16)wvv.y,
                       (_Float16)wvv.z, (_Float16)wvv.w };
            *(hf4*)&sm.a.w2_h[i * 4] = hv;
        } else if (t < 256 + 128 + QB) {
            const int i = t - (256 + 128);
            sm.a.qm_s[i] = q_mask[b * S1_ + q0 + i];
        }
        __syncthreads();

        // block-uniform q-activity flags (masked q -> output exactly 0)
        const bool qa0 = sm.a.qm_s[0] != 0.f;
        const bool qa1 = sm.a.qm_s[1] != 0.f;
        const bool qa2 = sm.a.qm_s[2] != 0.f;
        const bool qa3 = sm.a.qm_s[3] != 0.f;

        // phase 2a: score partials, prefetched kp stream
        float accs[QB] = {0.f, 0.f, 0.f, 0.f};
        const uint4* kp8 = (const uint4*)KPTh + ((size_t)b * 64 + hb * 32) * S2_ + k;

        uint4 kvu = kp8[0];
        for (int c = 0; c < 32; ++c) {
            uint4 nxt;
            if (c < 31) nxt = kp8[(size_t)(c + 1) * S2_];
            const int hoff = hb * (HM_ / 2) + c * 8;
            uint4 w4u = *(const uint4*)&sm.a.w2_h[hoff];
            hf2 kv0 = u2h(kvu.x), kv1 = u2h(kvu.y), kv2 = u2h(kvu.z), kv3 = u2h(kvu.w);
            hf2 wv0 = u2h(w4u.x), wv1 = u2h(w4u.y), wv2 = u2h(w4u.z), wv3 = u2h(w4u.w);
            const hf2 zero = (hf2)(_Float16)0;
#pragma unroll
            for (int q = 0; q < QB; ++q) {
                const bool act = (q == 0) ? qa0 : (q == 1) ? qa1 : (q == 2) ? qa2 : qa3;
                if (act) {
                    uint4 qvu = *(const uint4*)&sm.a.qp_h[q][hoff];
                    hf2 s;
                    s = __builtin_elementwise_max(u2h(qvu.x) + kv0, zero);
                    accs[q] = dot2(s, wv0, accs[q]);
                    s = __builtin_elementwise_max(u2h(qvu.y) + kv1, zero);
                    accs[q] = dot2(s, wv1, accs[q]);
                    s = __builtin_elementwise_max(u2h(qvu.z) + kv2, zero);
                    accs[q] = dot2(s, wv2, accs[q]);
                    s = __builtin_elementwise_max(u2h(qvu.w) + kv3, zero);
                    accs[q] = dot2(s, wv3, accs[q]);
                }
            }
            kvu = nxt;
        }
#pragma unroll
        for (int q = 0; q < QB; ++q) sm.a.Ap[hb][q][k] = accs[q];
        __syncthreads();

        // phase 2b: combine halves, mask, exp
        {
            const float b2v = b2[0];
#pragma unroll
            for (int i = 0; i < 2; ++i) {
                const int idx = t + i * 512;
                const int q = idx >> 8, kk = idx & 255;
                float sc = sm.a.Ap[0][q][kk] + sm.a.Ap[1][q][kk] + b2v;
                sm.a.Ap[0][q][kk] =
                    (sm.a.qm_s[q] * sm.a.km_s[kk] == 0.f) ? 0.f : __expf(sc);
            }
        }
        __syncthreads();

        // row sums
        if (t < QB * 64) {
            const int q = t >> 6, lane = t & 63;
            float p = sm.a.Ap[0][q][lane] + sm.a.Ap[0][q][lane + 64] +
                      sm.a.Ap[0][q][lane + 128] + sm.a.Ap[0][q][lane + 192];
#pragma unroll
            for (int m = 32; m >= 1; m >>= 1) p += __shfl_xor(p, m, 64);
            if (lane == 0) sm.a.rA_s[q] = 1.0f / fmaxf(p, 2e-15f);
        }
        __syncthreads();

        // PV with per-q uniform skip
        {
            const int w = t >> 6, lane = t & 63;
            const float4* vb = (const float4*)(value + (size_t)b * S2_ * H_)
                               + (size_t)(w * 32) * (H_ / 4) + lane;
            float4 o[QB];
#pragma unroll
            for (int q = 0; q < QB; ++q) o[q] = make_float4(0.f, 0.f, 0.f, 0.f);
#pragma unroll 4
            for (int kk = 0; kk < 32; ++kk) {
                float4 v = vb[(size_t)kk * (H_ / 4)];
#pragma unroll
                for (int q = 0; q < QB; ++q) {
                    const bool act = (q == 0) ? qa0 : (q == 1) ? qa1 : (q == 2) ? qa2 : qa3;
                    if (act) {
                        float a = sm.a.Ap[0][q][w * 32 + kk];
                        o[q].x = fmaf(a, v.x, o[q].x); o[q].y = fmaf(a, v.y, o[q].y);
                        o[q].z = fmaf(a, v.z, o[q].z); o[q].w = fmaf(a, v.w, o[q].w);
                    }
                }
            }
#pragma unroll
            for (int q = 0; q < QB; ++q) sm.a.opart[w][q][lane] = o[q];
        }
        __syncthreads();

        // combine 8 partials, normalize, store (masked q stores exact 0)
        if (t < QB * 64) {
            const int q = t >> 6, lane = t & 63;
            float4 s = make_float4(0.f, 0.f, 0.f, 0.f);
#pragma unroll
            for (int w = 0; w < 8; ++w) {
                float4 p = sm.a.opart[w][q][lane];
                s.x += p.x; s.y += p.y; s.z += p.z; s.w += p.w;
            }
            const float r = sm.a.rA_s[q];
            s.x *= r; s.y *= r; s.z *= r; s.w *= r;
            *(float4*)(out + (size_t)(b * S1_ + q0 + q) * H_ + lane * 4) = s;
        }
    }
}

extern "C" void kernel_launch(void* const* d_in, const int* in_sizes, int n_in,
                              void* d_out, int out_size, void* d_ws, size_t ws_size,
                              hipStream_t stream) {
    const float* query  = (const float*)d_in[0];  // [16,128,256]
    const float* key    = (const float*)d_in[1];  // [16,256,256]
    const float* value  = (const float*)d_in[2];  // [16,256,256]
    const float* q_mask = (const float*)d_in[3];  // [16,128]
    const float* k_mask = (const float*)d_in[4];  // [16,256]
    const float* W1     = (const float*)d_in[5];  // [512,512]
    const float* b1     = (const float*)d_in[6];  // [512]
    const float* W2     = (const float*)d_in[7];  // [512,1]
    const float* b2     = (const float*)d_in[8];  // [1]
    float*       out    = (float*)d_out;

    _Float16* QPh  = (_Float16*)d_ws;                  // [2048][512]      2 MB
    _Float16* KPTh = QPh  + (size_t)B_ * S1_ * HM_;    // [16][64][256][8] 4 MB
    _Float16* WB   = KPTh + (size_t)B_ * S2_ * HM_;    // frag-order W   0.5 MB
    unsigned* arr  = (unsigned*)(WB + (size_t)HM_ * HM_);   // [512]
    unsigned* go   = arr + NBLK;                            // [1]

    // zero the barrier flags each call (async, graph-capturable)
    hipMemsetAsync(arr, 0, (NBLK + 1) * sizeof(unsigned), stream);

    fused_kernel<<<NBLK, 512, 0, stream>>>(
        query, key, value, q_mask, k_mask, W1, b1, W2, b2,
        out, QPh, KPTh, WB, arr, go);
}

// Round 14
// 44.774 us; speedup vs baseline: 4.1532x; 4.0231x over previous
//
#include <hip/hip_runtime.h>
#include <hip/hip_bf16.h>

// Problem constants
#define B_  16
#define S1_ 128
#define S2_ 256
#define H_  256
#define HM_ 512
#define QB  4    // q-rows per attn block

typedef _Float16 hf2 __attribute__((ext_vector_type(2)));
typedef _Float16 hf4 __attribute__((ext_vector_type(4)));
typedef _Float16 hf8 __attribute__((ext_vector_type(8)));
typedef float    f32x4 __attribute__((ext_vector_type(4)));

static __device__ inline hf2 u2h(unsigned u) {
    union { unsigned u; hf2 h; } x; x.u = u; return x.h;
}

static __device__ inline float dot2(hf2 a, hf2 b, float c) {
#if __has_builtin(__builtin_amdgcn_fdot2)
    return __builtin_amdgcn_fdot2(a, b, c, false);
#else
    asm("v_dot2_f32_f16 %0, %1, %2, %0" : "+v"(c) : "v"(a), "v"(b));
    return c;
#endif
}

// ---------------------------------------------------------------------------
// proj: 768 blocks x 256 thr (4 waves). Inline W transpose (no cvtWB pass).
//   blocks [0,256):   QPh  = fp16( query @ W1[:256] )          [2048][512]
//   blocks [256,768): KPTh = fp16( key @ W1[256:] + b1 )  [b][h/8][k][8]
// 64x64 tile, FULL K=256 in LDS (one staging barrier), 8 unrolled MFMA
// steps (mfma_f32_16x16x32_f16). Wave tile 32x32. Epilogue via LDS C-tile
// so all global stores are coalesced uint4.
// ---------------------------------------------------------------------------
struct ProjStage {
    _Float16 Xh[64][264];
    _Float16 Wh[64][264];
};
union ProjU {
    ProjStage s;
    _Float16  Ct[64][72];   // epilogue C tile (aliases Xh after compute)
};

__global__ __launch_bounds__(256) void proj_kernel(
    const float* __restrict__ query,
    const float* __restrict__ key,
    const float* __restrict__ W1,
    const float* __restrict__ b1,
    _Float16* __restrict__ QPh,        // [2048][512]
    _Float16* __restrict__ KPTh)       // [16][64][256][8]
{
    __shared__ ProjU u;

    const int t   = threadIdx.x;
    const int bid = blockIdx.x;
    const bool modeK = bid >= 256;
    const int lb    = modeK ? bid - 256 : bid;
    const int mtile = lb >> 3, ntile = lb & 7;
    const int m0 = mtile * 64, n0 = ntile * 64;
    const float* X = modeK ? key : query;
    const float* W = W1 + (modeK ? (size_t)H_ * HM_ : 0);

    // stage X tile (64 m x 256 k), f32 -> f16, coalesced
#pragma unroll 2
    for (int i = 0; i < 8; ++i) {
        const int g   = t + i * 256;          // 0..2047 (8-half chunks)
        const int row = g >> 5, c8 = (g & 31) * 8;
        const float* xs = X + (size_t)(m0 + row) * H_ + c8;
        float4 xa = *(const float4*)xs;
        float4 xb = *(const float4*)(xs + 4);
        hf8 xh = { (_Float16)xa.x, (_Float16)xa.y, (_Float16)xa.z, (_Float16)xa.w,
                   (_Float16)xb.x, (_Float16)xb.y, (_Float16)xb.z, (_Float16)xb.w };
        *(hf8*)&u.s.Xh[row][c8] = xh;
    }
    // stage W tile transposed: Wh[n_local][k] = fp16(W[k][n0+n_local])
    // thread t, pass p: rows k2,k2+1; 4 n each; hf2 (4B, aligned) writes.
#pragma unroll 2
    for (int p = 0; p < 8; ++p) {
        const int k2 = p * 32 + (t >> 4) * 2;
        const int n4 = (t & 15) * 4;
        float4 wa = *(const float4*)(W + (size_t)k2 * HM_ + n0 + n4);
        float4 wb = *(const float4*)(W + (size_t)(k2 + 1) * HM_ + n0 + n4);
        const float* fa = (const float*)&wa;
        const float* fb = (const float*)&wb;
#pragma unroll
        for (int j = 0; j < 4; ++j) {
            hf2 pr = { (_Float16)fa[j], (_Float16)fb[j] };
            *(hf2*)&u.s.Wh[n4 + j][k2] = pr;
        }
    }
    __syncthreads();

    const int lane = t & 63, wid = t >> 6;
    const int wr = (wid >> 1) * 32;      // wave m-base
    const int wc = (wid & 1) * 32;       // wave n-base
    const int fr = lane & 15;
    const int fk = (lane >> 4) * 8;

    f32x4 acc[2][2] = {};

#pragma unroll
    for (int s = 0; s < 8; ++s) {
        const int kb = s * 32 + fk;
        hf8 a0  = *(const hf8*)&u.s.Xh[wr + fr][kb];
        hf8 a1  = *(const hf8*)&u.s.Xh[wr + 16 + fr][kb];
        hf8 b0  = *(const hf8*)&u.s.Wh[wc + fr][kb];
        hf8 b1v = *(const hf8*)&u.s.Wh[wc + 16 + fr][kb];
        acc[0][0] = __builtin_amdgcn_mfma_f32_16x16x32_f16(a0, b0,  acc[0][0], 0, 0, 0);
        acc[0][1] = __builtin_amdgcn_mfma_f32_16x16x32_f16(a0, b1v, acc[0][1], 0, 0, 0);
        acc[1][0] = __builtin_amdgcn_mfma_f32_16x16x32_f16(a1, b0,  acc[1][0], 0, 0, 0);
        acc[1][1] = __builtin_amdgcn_mfma_f32_16x16x32_f16(a1, b1v, acc[1][1], 0, 0, 0);
    }

    __syncthreads();   // staging reads done; alias LDS as C tile

    // scatter acc -> Ct[ml][nl] (fp16, bias folded in K mode)
    // D mapping (m89-verified): col = lane&15, row = (lane>>4)*4 + reg
#pragma unroll
    for (int i = 0; i < 2; ++i)
#pragma unroll
    for (int j = 0; j < 2; ++j) {
        const int nl = wc + j * 16 + fr;
        const float bv = modeK ? b1[n0 + nl] : 0.f;
#pragma unroll
        for (int r = 0; r < 4; ++r) {
            const int ml = wr + i * 16 + (lane >> 4) * 4 + r;
            u.Ct[ml][nl] = (_Float16)(acc[i][j][r] + bv);
        }
    }
    __syncthreads();

    // coalesced uint4 stores from the C tile (512 uint4, 2 per thread)
    if (!modeK) {
#pragma unroll
        for (int p = 0; p < 2; ++p) {
            const int idx = t + p * 256;           // 0..511
            const int row = idx >> 3, c = (idx & 7) * 8;
            *(uint4*)(QPh + (size_t)(m0 + row) * HM_ + n0 + c) =
                *(const uint4*)&u.Ct[row][c];
        }
    } else {
        const int bb = m0 >> 8, kbase = m0 & 255;
#pragma unroll
        for (int p = 0; p < 2; ++p) {
            const int idx = t + p * 256;           // 0..511
            const int h8l = idx >> 6, kl = idx & 63;
            const int h8  = (n0 >> 3) + h8l;
            *(uint4*)(KPTh + (((size_t)bb * 64 + h8) * 256 + kbase + kl) * 8) =
                *(const uint4*)&u.Ct[kl][h8l * 8];
        }
    }
}

// ---------------------------------------------------------------------------
// attn: block = (b, 4 q-rows), 512 threads: k = t&255, hb = t>>8.
// r13 improvements kept: block-uniform q-mask skip + kp prefetch.
// ---------------------------------------------------------------------------
__global__ __launch_bounds__(512, 4) void attn_kernel(
    const _Float16* __restrict__ QPh,  // [B*S1][HM]
    const _Float16* __restrict__ KPTh, // [B][HM/8][S2][8] (b1 folded)
    const float* __restrict__ value,   // [B, S2, H]
    const float* __restrict__ q_mask,  // [B, S1]
    const float* __restrict__ k_mask,  // [B, S2]
    const float* __restrict__ W2,      // [HM]
    const float* __restrict__ b2,      // [1]
    float* __restrict__ out)           // [B, S1, H]
{
    __shared__ __align__(16) _Float16 qp_h[QB][HM_];   // 4 KB
    __shared__ __align__(16) _Float16 w2_h[HM_];       // 1 KB
    __shared__ __align__(16) float    Ap[2][QB][S2_];  // 8 KB
    __shared__ __align__(16) float4   opart[8][QB][64];// 32 KB
    __shared__ float rA_s[QB];
    __shared__ float qm_s[QB];
    __shared__ float km_s[S2_];

    const int t  = threadIdx.x;
    const int k  = t & 255;
    const int hb = t >> 8;

    // XCD-aware swizzle: 512 blocks, XCD x gets 64 consecutive wg = 2 b's
    const int orig = blockIdx.x + (int)gridDim.x * blockIdx.y;  // 0..511
    const int wg   = (orig & 7) * 64 + (orig >> 3);
    const int q0   = (wg & 31) * QB;
    const int b    = wg >> 5;

    if (t < 256) {
        const uint4* src = (const uint4*)(QPh + (size_t)(b * S1_ + q0) * HM_);
        ((uint4*)&qp_h[0][0])[t] = src[t];
        km_s[t] = k_mask[b * S2_ + t];
    } else if (t < 256 + 128) {
        const int i = t - 256;
        float4 wvv = ((const float4*)W2)[i];
        hf4 hv = { (_Float16)wvv.x, (_Float16)wvv.y,
                   (_Float16)wvv.z, (_Float16)wvv.w };
        *(hf4*)&w2_h[i * 4] = hv;
    } else if (t < 256 + 128 + QB) {
        const int i = t - (256 + 128);
        qm_s[i] = q_mask[b * S1_ + q0 + i];
    }
    __syncthreads();

    // block-uniform q-activity flags (masked q -> output exactly 0)
    const bool qa0 = qm_s[0] != 0.f;
    const bool qa1 = qm_s[1] != 0.f;
    const bool qa2 = qm_s[2] != 0.f;
    const bool qa3 = qm_s[3] != 0.f;

    // phase 1: score partials, prefetched kp stream (32 chunks of 8 h)
    float accs[QB] = {0.f, 0.f, 0.f, 0.f};
    const uint4* kp8 = (const uint4*)KPTh + ((size_t)b * 64 + hb * 32) * S2_ + k;

    uint4 kvu = kp8[0];
    for (int c = 0; c < 32; ++c) {
        uint4 nxt;
        if (c < 31) nxt = kp8[(size_t)(c + 1) * S2_];
        const int hoff = hb * (HM_ / 2) + c * 8;
        uint4 w4u = *(const uint4*)&w2_h[hoff];
        hf2 kv0 = u2h(kvu.x), kv1 = u2h(kvu.y), kv2 = u2h(kvu.z), kv3 = u2h(kvu.w);
        hf2 wv0 = u2h(w4u.x), wv1 = u2h(w4u.y), wv2 = u2h(w4u.z), wv3 = u2h(w4u.w);
        const hf2 zero = (hf2)(_Float16)0;
#pragma unroll
        for (int q = 0; q < QB; ++q) {
            const bool act = (q == 0) ? qa0 : (q == 1) ? qa1 : (q == 2) ? qa2 : qa3;
            if (act) {
                uint4 qvu = *(const uint4*)&qp_h[q][hoff];
                hf2 s;
                s = __builtin_elementwise_max(u2h(qvu.x) + kv0, zero);
                accs[q] = dot2(s, wv0, accs[q]);
                s = __builtin_elementwise_max(u2h(qvu.y) + kv1, zero);
                accs[q] = dot2(s, wv1, accs[q]);
                s = __builtin_elementwise_max(u2h(qvu.z) + kv2, zero);
                accs[q] = dot2(s, wv2, accs[q]);
                s = __builtin_elementwise_max(u2h(qvu.w) + kv3, zero);
                accs[q] = dot2(s, wv3, accs[q]);
            }
        }
        kvu = nxt;
    }
#pragma unroll
    for (int q = 0; q < QB; ++q) Ap[hb][q][k] = accs[q];
    __syncthreads();

    // phase 2: combine halves, mask, exp
    {
        const float b2v = b2[0];
#pragma unroll
        for (int i = 0; i < 2; ++i) {
            const int idx = t + i * 512;
            const int q = idx >> 8, kk = idx & 255;
            float sc = Ap[0][q][kk] + Ap[1][q][kk] + b2v;
            Ap[0][q][kk] = (qm_s[q] * km_s[kk] == 0.f) ? 0.f : __expf(sc);
        }
    }
    __syncthreads();

    // row sums
    if (t < QB * 64) {
        const int q = t >> 6, lane = t & 63;
        float p = Ap[0][q][lane] + Ap[0][q][lane + 64] +
                  Ap[0][q][lane + 128] + Ap[0][q][lane + 192];
#pragma unroll
        for (int m = 32; m >= 1; m >>= 1) p += __shfl_xor(p, m, 64);
        if (lane == 0) rA_s[q] = 1.0f / fmaxf(p, 2e-15f);
    }
    __syncthreads();

    // PV with per-q uniform skip
    {
        const int w = t >> 6, lane = t & 63;
        const float4* vb = (const float4*)(value + (size_t)b * S2_ * H_)
                           + (size_t)(w * 32) * (H_ / 4) + lane;
        float4 o[QB];
#pragma unroll
        for (int q = 0; q < QB; ++q) o[q] = make_float4(0.f, 0.f, 0.f, 0.f);
#pragma unroll 4
        for (int kk = 0; kk < 32; ++kk) {
            float4 v = vb[(size_t)kk * (H_ / 4)];
#pragma unroll
            for (int q = 0; q < QB; ++q) {
                const bool act = (q == 0) ? qa0 : (q == 1) ? qa1 : (q == 2) ? qa2 : qa3;
                if (act) {
                    float a = Ap[0][q][w * 32 + kk];
                    o[q].x = fmaf(a, v.x, o[q].x); o[q].y = fmaf(a, v.y, o[q].y);
                    o[q].z = fmaf(a, v.z, o[q].z); o[q].w = fmaf(a, v.w, o[q].w);
                }
            }
        }
#pragma unroll
        for (int q = 0; q < QB; ++q) opart[w][q][lane] = o[q];
    }
    __syncthreads();

    // combine 8 partials, normalize, store (masked q stores exact 0)
    if (t < QB * 64) {
        const int q = t >> 6, lane = t & 63;
        float4 s = make_float4(0.f, 0.f, 0.f, 0.f);
#pragma unroll
        for (int w = 0; w < 8; ++w) {
            float4 p = opart[w][q][lane];
            s.x += p.x; s.y += p.y; s.z += p.z; s.w += p.w;
        }
        const float r = rA_s[q];
        s.x *= r; s.y *= r; s.z *= r; s.w *= r;
        *(float4*)(out + (size_t)(b * S1_ + q0 + q) * H_ + lane * 4) = s;
    }
}

extern "C" void kernel_launch(void* const* d_in, const int* in_sizes, int n_in,
                              void* d_out, int out_size, void* d_ws, size_t ws_size,
                              hipStream_t stream) {
    const float* query  = (const float*)d_in[0];  // [16,128,256]
    const float* key    = (const float*)d_in[1];  // [16,256,256]
    const float* value  = (const float*)d_in[2];  // [16,256,256]
    const float* q_mask = (const float*)d_in[3];  // [16,128]
    const float* k_mask = (const float*)d_in[4];  // [16,256]
    const float* W1     = (const float*)d_in[5];  // [512,512]
    const float* b1     = (const float*)d_in[6];  // [512]
    const float* W2     = (const float*)d_in[7];  // [512,1]
    const float* b2     = (const float*)d_in[8];  // [1]
    float*       out    = (float*)d_out;

    _Float16* QPh  = (_Float16*)d_ws;                  // [2048][512]      2 MB
    _Float16* KPTh = QPh + (size_t)B_ * S1_ * HM_;     // [16][64][256][8] 4 MB

    // merged projections with inline W transpose (2-dispatch pipeline)
    proj_kernel<<<768, 256, 0, stream>>>(query, key, W1, b1, QPh, KPTh);

    attn_kernel<<<dim3(S1_ / QB, B_), 512, 0, stream>>>(
        QPh, KPTh, value, q_mask, k_mask, W2, b2, out);
}

// Round 15
// 44.606 us; speedup vs baseline: 4.1689x; 1.0038x over previous
//
#include <hip/hip_runtime.h>
#include <hip/hip_bf16.h>

// Problem constants
#define B_  16
#define S1_ 128
#define S2_ 256
#define H_  256
#define HM_ 512
#define QB  4    // q-rows per attn block

typedef _Float16 hf2 __attribute__((ext_vector_type(2)));
typedef _Float16 hf4 __attribute__((ext_vector_type(4)));
typedef _Float16 hf8 __attribute__((ext_vector_type(8)));
typedef float    f32x4 __attribute__((ext_vector_type(4)));

static __device__ inline hf2 u2h(unsigned u) {
    union { unsigned u; hf2 h; } x; x.u = u; return x.h;
}

static __device__ inline float dot2(hf2 a, hf2 b, float c) {
#if __has_builtin(__builtin_amdgcn_fdot2)
    return __builtin_amdgcn_fdot2(a, b, c, false);
#else
    asm("v_dot2_f32_f16 %0, %1, %2, %0" : "+v"(c) : "v"(a), "v"(b));
    return c;
#endif
}

// ---------------------------------------------------------------------------
// cvtWB: repack W1 [512 k][512 n] f32 into MFMA B-fragment order, fp16
// (r10 verbatim — fastest measured proj chain).
// ---------------------------------------------------------------------------
__global__ __launch_bounds__(256) void cvtWB_kernel(
    const float* __restrict__ W1, _Float16* __restrict__ WB)
{
    const int idx  = blockIdx.x * 256 + threadIdx.x;  // 0..32767
    const int lane = idx & 63;
    const int nblk = (idx >> 6) & 31;
    const int kblk = idx >> 11;                       // 0..15
    const int n    = nblk * 16 + (lane & 15);
    const int k0   = kblk * 32 + (lane >> 4) * 8;
    hf8 v;
#pragma unroll
    for (int j = 0; j < 8; ++j)
        v[j] = (_Float16)W1[(size_t)(k0 + j) * HM_ + n];
    *(hf8*)(WB + (size_t)idx * 8) = v;
}

// ---------------------------------------------------------------------------
// proj_mfma: grid 384 blocks x 512 thr (8 waves) — r10 verbatim.
//   blocks [0,128):   QPh  = fp16( query @ W1[:256] )       [2048][512]
//   blocks [128,384): KPTh = fp16( key @ W1[256:] + b1 ) [b][h/8][k][8]
// Block tile: 16 m-rows x ALL 512 n. B from WB (frag-order, coalesced,
// L2-resident). Epilogue via LDS [16][512] fp16 tile -> coalesced uint4.
// ---------------------------------------------------------------------------
#define ESTR 520   // LDS row stride in halves

__global__ __launch_bounds__(512, 4) void proj_mfma_kernel(
    const float* __restrict__ query,
    const float* __restrict__ key,
    const _Float16* __restrict__ WB,
    const float* __restrict__ b1,
    _Float16* __restrict__ QPh,        // [2048][512]
    _Float16* __restrict__ KPTh)       // [16][64][256][8]
{
    __shared__ _Float16 Es[16 * ESTR];   // 16.6 KB: X tile, then C tile

    const int t   = threadIdx.x;
    const int bid = blockIdx.x;
    const bool modeK = bid >= 128;
    const int m0  = (modeK ? bid - 128 : bid) * 16;
    const float* X = modeK ? key : query;
    const int kb  = modeK ? 8 : 0;

    // stage X tile (16 rows x 256 k), fp32 -> fp16
    {
        const int row = t >> 5, c8 = (t & 31) * 8;
        const float* xs = X + (size_t)(m0 + row) * H_ + c8;
        float4 xa = *(const float4*)xs;
        float4 xb = *(const float4*)(xs + 4);
        hf8 xh = { (_Float16)xa.x, (_Float16)xa.y, (_Float16)xa.z, (_Float16)xa.w,
                   (_Float16)xb.x, (_Float16)xb.y, (_Float16)xb.z, (_Float16)xb.w };
        *(hf8*)&Es[row * ESTR + c8] = xh;
    }
    __syncthreads();

    const int lane = t & 63, w = t >> 6;
    const int fr = lane & 15;
    const int fk = (lane >> 4) * 8;

    f32x4 acc[4] = {};

#pragma unroll
    for (int s = 0; s < 8; ++s) {
        hf8 a = *(const hf8*)&Es[fr * ESTR + s * 32 + fk];
        const _Float16* bp =
            WB + ((((size_t)(kb + s) * 32 + w * 4) * 64) + lane) * 8;
#pragma unroll
        for (int nf = 0; nf < 4; ++nf) {
            hf8 bv = *(const hf8*)(bp + (size_t)nf * 64 * 8);
            acc[nf] = __builtin_amdgcn_mfma_f32_16x16x32_f16(a, bv, acc[nf], 0, 0, 0);
        }
    }

    __syncthreads();     // X-tile reads complete; reuse Es as C tile

    // scatter acc -> Es[mlocal][n] (fp16, bias folded for K mode)
#pragma unroll
    for (int nf = 0; nf < 4; ++nf) {
        const int n = w * 64 + nf * 16 + fr;
        const float bv = modeK ? b1[n] : 0.f;
#pragma unroll
        for (int r = 0; r < 4; ++r) {
            const int ml = (lane >> 4) * 4 + r;      // D row = (lane>>4)*4+reg
            Es[ml * ESTR + n] = (_Float16)(acc[nf][r] + bv);
        }
    }
    __syncthreads();

    // coalesced stores from the C tile
    if (!modeK) {
        // QPh: 16 rows x 64 uint4 = 1024 uint4, 2 per thread
#pragma unroll
        for (int p = 0; p < 2; ++p) {
            const int idx = t + p * 512;
            const int row = idx >> 6, c8 = (idx & 63) * 8;
            *(uint4*)(QPh + (size_t)(m0 + row) * HM_ + c8) =
                *(const uint4*)&Es[row * ESTR + c8];
        }
    } else {
        const int bb = m0 >> 8, kbase = m0 & 255;
#pragma unroll
        for (int p = 0; p < 2; ++p) {
            const int idx = t + p * 512;
            const int h8 = idx >> 4, kl = idx & 15;
            *(uint4*)(KPTh + (((size_t)bb * 64 + h8) * 256 + kbase + kl) * 8) =
                *(const uint4*)&Es[kl * ESTR + h8 * 8];
        }
    }
}

// ---------------------------------------------------------------------------
// attn: r14 version (q-mask uniform skip + kp prefetch).
// ---------------------------------------------------------------------------
__global__ __launch_bounds__(512, 4) void attn_kernel(
    const _Float16* __restrict__ QPh,  // [B*S1][HM]
    const _Float16* __restrict__ KPTh, // [B][HM/8][S2][8] (b1 folded)
    const float* __restrict__ value,   // [B, S2, H]
    const float* __restrict__ q_mask,  // [B, S1]
    const float* __restrict__ k_mask,  // [B, S2]
    const float* __restrict__ W2,      // [HM]
    const float* __restrict__ b2,      // [1]
    float* __restrict__ out)           // [B, S1, H]
{
    __shared__ __align__(16) _Float16 qp_h[QB][HM_];   // 4 KB
    __shared__ __align__(16) _Float16 w2_h[HM_];       // 1 KB
    __shared__ __align__(16) float    Ap[2][QB][S2_];  // 8 KB
    __shared__ __align__(16) float4   opart[8][QB][64];// 32 KB
    __shared__ float rA_s[QB];
    __shared__ float qm_s[QB];
    __shared__ float km_s[S2_];

    const int t  = threadIdx.x;
    const int k  = t & 255;
    const int hb = t >> 8;

    // XCD-aware swizzle: 512 blocks, XCD x gets 64 consecutive wg = 2 b's
    const int orig = blockIdx.x + (int)gridDim.x * blockIdx.y;  // 0..511
    const int wg   = (orig & 7) * 64 + (orig >> 3);
    const int q0   = (wg & 31) * QB;
    const int b    = wg >> 5;

    if (t < 256) {
        const uint4* src = (const uint4*)(QPh + (size_t)(b * S1_ + q0) * HM_);
        ((uint4*)&qp_h[0][0])[t] = src[t];
        km_s[t] = k_mask[b * S2_ + t];
    } else if (t < 256 + 128) {
        const int i = t - 256;
        float4 wvv = ((const float4*)W2)[i];
        hf4 hv = { (_Float16)wvv.x, (_Float16)wvv.y,
                   (_Float16)wvv.z, (_Float16)wvv.w };
        *(hf4*)&w2_h[i * 4] = hv;
    } else if (t < 256 + 128 + QB) {
        const int i = t - (256 + 128);
        qm_s[i] = q_mask[b * S1_ + q0 + i];
    }
    __syncthreads();

    // block-uniform q-activity flags (masked q -> output exactly 0)
    const bool qa0 = qm_s[0] != 0.f;
    const bool qa1 = qm_s[1] != 0.f;
    const bool qa2 = qm_s[2] != 0.f;
    const bool qa3 = qm_s[3] != 0.f;

    // phase 1: score partials, prefetched kp stream (32 chunks of 8 h)
    float accs[QB] = {0.f, 0.f, 0.f, 0.f};
    const uint4* kp8 = (const uint4*)KPTh + ((size_t)b * 64 + hb * 32) * S2_ + k;

    uint4 kvu = kp8[0];
    for (int c = 0; c < 32; ++c) {
        uint4 nxt;
        if (c < 31) nxt = kp8[(size_t)(c + 1) * S2_];
        const int hoff = hb * (HM_ / 2) + c * 8;
        uint4 w4u = *(const uint4*)&w2_h[hoff];
        hf2 kv0 = u2h(kvu.x), kv1 = u2h(kvu.y), kv2 = u2h(kvu.z), kv3 = u2h(kvu.w);
        hf2 wv0 = u2h(w4u.x), wv1 = u2h(w4u.y), wv2 = u2h(w4u.z), wv3 = u2h(w4u.w);
        const hf2 zero = (hf2)(_Float16)0;
#pragma unroll
        for (int q = 0; q < QB; ++q) {
            const bool act = (q == 0) ? qa0 : (q == 1) ? qa1 : (q == 2) ? qa2 : qa3;
            if (act) {
                uint4 qvu = *(const uint4*)&qp_h[q][hoff];
                hf2 s;
                s = __builtin_elementwise_max(u2h(qvu.x) + kv0, zero);
                accs[q] = dot2(s, wv0, accs[q]);
                s = __builtin_elementwise_max(u2h(qvu.y) + kv1, zero);
                accs[q] = dot2(s, wv1, accs[q]);
                s = __builtin_elementwise_max(u2h(qvu.z) + kv2, zero);
                accs[q] = dot2(s, wv2, accs[q]);
                s = __builtin_elementwise_max(u2h(qvu.w) + kv3, zero);
                accs[q] = dot2(s, wv3, accs[q]);
            }
        }
        kvu = nxt;
    }
#pragma unroll
    for (int q = 0; q < QB; ++q) Ap[hb][q][k] = accs[q];
    __syncthreads();

    // phase 2: combine halves, mask, exp
    {
        const float b2v = b2[0];
#pragma unroll
        for (int i = 0; i < 2; ++i) {
            const int idx = t + i * 512;
            const int q = idx >> 8, kk = idx & 255;
            float sc = Ap[0][q][kk] + Ap[1][q][kk] + b2v;
            Ap[0][q][kk] = (qm_s[q] * km_s[kk] == 0.f) ? 0.f : __expf(sc);
        }
    }
    __syncthreads();

    // row sums
    if (t < QB * 64) {
        const int q = t >> 6, lane = t & 63;
        float p = Ap[0][q][lane] + Ap[0][q][lane + 64] +
                  Ap[0][q][lane + 128] + Ap[0][q][lane + 192];
#pragma unroll
        for (int m = 32; m >= 1; m >>= 1) p += __shfl_xor(p, m, 64);
        if (lane == 0) rA_s[q] = 1.0f / fmaxf(p, 2e-15f);
    }
    __syncthreads();

    // PV with per-q uniform skip
    {
        const int w = t >> 6, lane = t & 63;
        const float4* vb = (const float4*)(value + (size_t)b * S2_ * H_)
                           + (size_t)(w * 32) * (H_ / 4) + lane;
        float4 o[QB];
#pragma unroll
        for (int q = 0; q < QB; ++q) o[q] = make_float4(0.f, 0.f, 0.f, 0.f);
#pragma unroll 4
        for (int kk = 0; kk < 32; ++kk) {
            float4 v = vb[(size_t)kk * (H_ / 4)];
#pragma unroll
            for (int q = 0; q < QB; ++q) {
                const bool act = (q == 0) ? qa0 : (q == 1) ? qa1 : (q == 2) ? qa2 : qa3;
                if (act) {
                    float a = Ap[0][q][w * 32 + kk];
                    o[q].x = fmaf(a, v.x, o[q].x); o[q].y = fmaf(a, v.y, o[q].y);
                    o[q].z = fmaf(a, v.z, o[q].z); o[q].w = fmaf(a, v.w, o[q].w);
                }
            }
        }
#pragma unroll
        for (int q = 0; q < QB; ++q) opart[w][q][lane] = o[q];
    }
    __syncthreads();

    // combine 8 partials, normalize, store (masked q stores exact 0)
    if (t < QB * 64) {
        const int q = t >> 6, lane = t & 63;
        float4 s = make_float4(0.f, 0.f, 0.f, 0.f);
#pragma unroll
        for (int w = 0; w < 8; ++w) {
            float4 p = opart[w][q][lane];
            s.x += p.x; s.y += p.y; s.z += p.z; s.w += p.w;
        }
        const float r = rA_s[q];
        s.x *= r; s.y *= r; s.z *= r; s.w *= r;
        *(float4*)(out + (size_t)(b * S1_ + q0 + q) * H_ + lane * 4) = s;
    }
}

extern "C" void kernel_launch(void* const* d_in, const int* in_sizes, int n_in,
                              void* d_out, int out_size, void* d_ws, size_t ws_size,
                              hipStream_t stream) {
    const float* query  = (const float*)d_in[0];  // [16,128,256]
    const float* key    = (const float*)d_in[1];  // [16,256,256]
    const float* value  = (const float*)d_in[2];  // [16,256,256]
    const float* q_mask = (const float*)d_in[3];  // [16,128]
    const float* k_mask = (const float*)d_in[4];  // [16,256]
    const float* W1     = (const float*)d_in[5];  // [512,512]
    const float* b1     = (const float*)d_in[6];  // [512]
    const float* W2     = (const float*)d_in[7];  // [512,1]
    const float* b2     = (const float*)d_in[8];  // [1]
    float*       out    = (float*)d_out;

    _Float16* QPh  = (_Float16*)d_ws;                  // [2048][512]      2 MB
    _Float16* KPTh = QPh  + (size_t)B_ * S1_ * HM_;    // [16][64][256][8] 4 MB
    _Float16* WB   = KPTh + (size_t)B_ * S2_ * HM_;    // frag-order W   0.5 MB

    cvtWB_kernel<<<128, 256, 0, stream>>>(W1, WB);

    proj_mfma_kernel<<<384, 512, 0, stream>>>(query, key, WB, b1, QPh, KPTh);

    attn_kernel<<<dim3(S1_ / QB, B_), 512, 0, stream>>>(
        QPh, KPTh, value, q_mask, k_mask, W2, b2, out);
}

// Round 16
// 42.135 us; speedup vs baseline: 4.4133x; 1.0586x over previous
//
#include <hip/hip_runtime.h>
#include <hip/hip_bf16.h>

// Problem constants
#define B_  16
#define S1_ 128
#define S2_ 256
#define H_  256
#define HM_ 512
#define QB  4    // q-rows per attn block

typedef _Float16 hf2 __attribute__((ext_vector_type(2)));
typedef _Float16 hf4 __attribute__((ext_vector_type(4)));
typedef _Float16 hf8 __attribute__((ext_vector_type(8)));
typedef float    f32x4 __attribute__((ext_vector_type(4)));

static __device__ inline hf2 u2h(unsigned u) {
    union { unsigned u; hf2 h; } x; x.u = u; return x.h;
}

static __device__ inline float dot2(hf2 a, hf2 b, float c) {
#if __has_builtin(__builtin_amdgcn_fdot2)
    return __builtin_amdgcn_fdot2(a, b, c, false);
#else
    asm("v_dot2_f32_f16 %0, %1, %2, %0" : "+v"(c) : "v"(a), "v"(b));
    return c;
#endif
}

// ---------------------------------------------------------------------------
// cvtWB: repack W1 [512 k][512 n] f32 into MFMA B-fragment order, fp16
// (r10 verbatim).
// ---------------------------------------------------------------------------
__global__ __launch_bounds__(256) void cvtWB_kernel(
    const float* __restrict__ W1, _Float16* __restrict__ WB)
{
    const int idx  = blockIdx.x * 256 + threadIdx.x;  // 0..32767
    const int lane = idx & 63;
    const int nblk = (idx >> 6) & 31;
    const int kblk = idx >> 11;                       // 0..15
    const int n    = nblk * 16 + (lane & 15);
    const int k0   = kblk * 32 + (lane >> 4) * 8;
    hf8 v;
#pragma unroll
    for (int j = 0; j < 8; ++j)
        v[j] = (_Float16)W1[(size_t)(k0 + j) * HM_ + n];
    *(hf8*)(WB + (size_t)idx * 8) = v;
}

// ---------------------------------------------------------------------------
// proj_mfma: grid 384 blocks x 512 thr (8 waves) — r10 verbatim.
//   blocks [0,128):   QPh  = fp16( query @ W1[:256] )       [2048][512]
//   blocks [128,384): KPTh = fp16( key @ W1[256:] + b1 ) [b][h/8][k][8]
// ---------------------------------------------------------------------------
#define ESTR 520   // LDS row stride in halves

__global__ __launch_bounds__(512, 4) void proj_mfma_kernel(
    const float* __restrict__ query,
    const float* __restrict__ key,
    const _Float16* __restrict__ WB,
    const float* __restrict__ b1,
    _Float16* __restrict__ QPh,        // [2048][512]
    _Float16* __restrict__ KPTh)       // [16][64][256][8]
{
    __shared__ _Float16 Es[16 * ESTR];   // 16.6 KB: X tile, then C tile

    const int t   = threadIdx.x;
    const int bid = blockIdx.x;
    const bool modeK = bid >= 128;
    const int m0  = (modeK ? bid - 128 : bid) * 16;
    const float* X = modeK ? key : query;
    const int kb  = modeK ? 8 : 0;

    // stage X tile (16 rows x 256 k), fp32 -> fp16
    {
        const int row = t >> 5, c8 = (t & 31) * 8;
        const float* xs = X + (size_t)(m0 + row) * H_ + c8;
        float4 xa = *(const float4*)xs;
        float4 xb = *(const float4*)(xs + 4);
        hf8 xh = { (_Float16)xa.x, (_Float16)xa.y, (_Float16)xa.z, (_Float16)xa.w,
                   (_Float16)xb.x, (_Float16)xb.y, (_Float16)xb.z, (_Float16)xb.w };
        *(hf8*)&Es[row * ESTR + c8] = xh;
    }
    __syncthreads();

    const int lane = t & 63, w = t >> 6;
    const int fr = lane & 15;
    const int fk = (lane >> 4) * 8;

    f32x4 acc[4] = {};

#pragma unroll
    for (int s = 0; s < 8; ++s) {
        hf8 a = *(const hf8*)&Es[fr * ESTR + s * 32 + fk];
        const _Float16* bp =
            WB + ((((size_t)(kb + s) * 32 + w * 4) * 64) + lane) * 8;
#pragma unroll
        for (int nf = 0; nf < 4; ++nf) {
            hf8 bv = *(const hf8*)(bp + (size_t)nf * 64 * 8);
            acc[nf] = __builtin_amdgcn_mfma_f32_16x16x32_f16(a, bv, acc[nf], 0, 0, 0);
        }
    }

    __syncthreads();     // X-tile reads complete; reuse Es as C tile

    // scatter acc -> Es[mlocal][n] (fp16, bias folded for K mode)
#pragma unroll
    for (int nf = 0; nf < 4; ++nf) {
        const int n = w * 64 + nf * 16 + fr;
        const float bv = modeK ? b1[n] : 0.f;
#pragma unroll
        for (int r = 0; r < 4; ++r) {
            const int ml = (lane >> 4) * 4 + r;      // D row = (lane>>4)*4+reg
            Es[ml * ESTR + n] = (_Float16)(acc[nf][r] + bv);
        }
    }
    __syncthreads();

    // coalesced stores from the C tile
    if (!modeK) {
        // QPh: 16 rows x 64 uint4 = 1024 uint4, 2 per thread
#pragma unroll
        for (int p = 0; p < 2; ++p) {
            const int idx = t + p * 512;
            const int row = idx >> 6, c8 = (idx & 63) * 8;
            *(uint4*)(QPh + (size_t)(m0 + row) * HM_ + c8) =
                *(const uint4*)&Es[row * ESTR + c8];
        }
    } else {
        const int bb = m0 >> 8, kbase = m0 & 255;
#pragma unroll
        for (int p = 0; p < 2; ++p) {
            const int idx = t + p * 512;
            const int h8 = idx >> 4, kl = idx & 15;
            *(uint4*)(KPTh + (((size_t)bb * 64 + h8) * 256 + kbase + kl) * 8) =
                *(const uint4*)&Es[kl * ESTR + h8 * 8];
        }
    }
}

// ---------------------------------------------------------------------------
// attn: r10 version + ONE change: wave-uniform k_mask skip in PV
// (km_s[w*32+kk] identical across the wave -> s_cbranch skips value load).
// ---------------------------------------------------------------------------
__global__ __launch_bounds__(512, 4) void attn_kernel(
    const _Float16* __restrict__ QPh,  // [B*S1][HM]
    const _Float16* __restrict__ KPTh, // [B][HM/8][S2][8] (b1 folded)
    const float* __restrict__ value,   // [B, S2, H]
    const float* __restrict__ q_mask,  // [B, S1]
    const float* __restrict__ k_mask,  // [B, S2]
    const float* __restrict__ W2,      // [HM]
    const float* __restrict__ b2,      // [1]
    float* __restrict__ out)           // [B, S1, H]
{
    __shared__ __align__(16) _Float16 qp_h[QB][HM_];   // 4 KB
    __shared__ __align__(16) _Float16 w2_h[HM_];       // 1 KB
    __shared__ __align__(16) float    Ap[2][QB][S2_];  // 8 KB
    __shared__ __align__(16) float4   opart[8][QB][64];// 32 KB
    __shared__ float rA_s[QB];
    __shared__ float qm_s[QB];
    __shared__ float km_s[S2_];

    const int t  = threadIdx.x;
    const int k  = t & 255;
    const int hb = t >> 8;

    // XCD-aware swizzle: 512 blocks, XCD x gets 64 consecutive wg = 2 b's
    const int orig = blockIdx.x + (int)gridDim.x * blockIdx.y;  // 0..511
    const int wg   = (orig & 7) * 64 + (orig >> 3);
    const int q0   = (wg & 31) * QB;
    const int b    = wg >> 5;

    // stage qp (fp16), w2 (cvt), masks
    {
        if (t < 256) {
            const uint4* src = (const uint4*)(QPh + (size_t)(b * S1_ + q0) * HM_);
            ((uint4*)&qp_h[0][0])[t] = src[t];
            km_s[t] = k_mask[b * S2_ + t];
        } else if (t < 256 + 128) {
            const int i = t - 256;
            float4 wvv = ((const float4*)W2)[i];
            hf4 hv = { (_Float16)wvv.x, (_Float16)wvv.y,
                       (_Float16)wvv.z, (_Float16)wvv.w };
            *(hf4*)&w2_h[i * 4] = hv;
        } else if (t < 256 + 128 + QB) {
            const int i = t - (256 + 128);
            qm_s[i] = q_mask[b * S1_ + q0 + i];
        }
    }
    __syncthreads();

    // phase 1: score partials over this thread's h half (32 chunks of 8 h)
    float accs[QB] = {0.f, 0.f, 0.f, 0.f};
    const uint4* kp8 = (const uint4*)KPTh + ((size_t)b * 64 + hb * 32) * S2_ + k;

    for (int c = 0; c < 32; ++c) {
        uint4 kvu = kp8[(size_t)c * S2_];
        const int hoff = hb * (HM_ / 2) + c * 8;
        uint4 w4u = *(const uint4*)&w2_h[hoff];
        hf2 kv0 = u2h(kvu.x), kv1 = u2h(kvu.y), kv2 = u2h(kvu.z), kv3 = u2h(kvu.w);
        hf2 wv0 = u2h(w4u.x), wv1 = u2h(w4u.y), wv2 = u2h(w4u.z), wv3 = u2h(w4u.w);
        const hf2 zero = (hf2)(_Float16)0;
#pragma unroll
        for (int q = 0; q < QB; ++q) {
            uint4 qvu = *(const uint4*)&qp_h[q][hoff];
            hf2 s;
            s = __builtin_elementwise_max(u2h(qvu.x) + kv0, zero);
            accs[q] = dot2(s, wv0, accs[q]);
            s = __builtin_elementwise_max(u2h(qvu.y) + kv1, zero);
            accs[q] = dot2(s, wv1, accs[q]);
            s = __builtin_elementwise_max(u2h(qvu.z) + kv2, zero);
            accs[q] = dot2(s, wv2, accs[q]);
            s = __builtin_elementwise_max(u2h(qvu.w) + kv3, zero);
            accs[q] = dot2(s, wv3, accs[q]);
        }
    }
#pragma unroll
    for (int q = 0; q < QB; ++q) Ap[hb][q][k] = accs[q];
    __syncthreads();

    // phase 2: combine halves, mask, exp (in place into Ap[0])
    {
        const float b2v = b2[0];
#pragma unroll
        for (int i = 0; i < 2; ++i) {
            const int idx = t + i * 512;           // 0..1023
            const int q = idx >> 8, kk = idx & 255;
            float sc = Ap[0][q][kk] + Ap[1][q][kk] + b2v;
            Ap[0][q][kk] = (qm_s[q] * km_s[kk] == 0.f) ? 0.f : __expf(sc);
        }
    }
    __syncthreads();

    // row sums: waves 0..3 (one per q-row), 64-lane butterfly
    if (t < QB * 64) {
        const int q = t >> 6, lane = t & 63;
        float p = Ap[0][q][lane] + Ap[0][q][lane + 64] +
                  Ap[0][q][lane + 128] + Ap[0][q][lane + 192];
#pragma unroll
        for (int m = 32; m >= 1; m >>= 1) p += __shfl_xor(p, m, 64);
        if (lane == 0) rA_s[q] = 1.0f / fmaxf(p, 2e-15f);
    }
    __syncthreads();

    // PV: wave w owns value rows [w*32, w*32+32) for ALL 4 q.
    // NEW: skip masked k rows — km_s[w*32+kk] is wave-uniform, so this is a
    // scalar branch skipping the 1KB value load + 16 FMAs (~50% of rows).
    {
        const int w = t >> 6, lane = t & 63;
        const float4* vb = (const float4*)(value + (size_t)b * S2_ * H_)
                           + (size_t)(w * 32) * (H_ / 4) + lane;
        float4 o[QB];
#pragma unroll
        for (int q = 0; q < QB; ++q) o[q] = make_float4(0.f, 0.f, 0.f, 0.f);
        for (int kk = 0; kk < 32; ++kk) {
            if (km_s[w * 32 + kk] != 0.f) {
                float4 v = vb[(size_t)kk * (H_ / 4)];
#pragma unroll
                for (int q = 0; q < QB; ++q) {
                    float a = Ap[0][q][w * 32 + kk];
                    o[q].x = fmaf(a, v.x, o[q].x); o[q].y = fmaf(a, v.y, o[q].y);
                    o[q].z = fmaf(a, v.z, o[q].z); o[q].w = fmaf(a, v.w, o[q].w);
                }
            }
        }
#pragma unroll
        for (int q = 0; q < QB; ++q) opart[w][q][lane] = o[q];
    }
    __syncthreads();

    // combine 8 partials, normalize, store
    if (t < QB * 64) {
        const int q = t >> 6, lane = t & 63;
        float4 s = make_float4(0.f, 0.f, 0.f, 0.f);
#pragma unroll
        for (int w = 0; w < 8; ++w) {
            float4 p = opart[w][q][lane];
            s.x += p.x; s.y += p.y; s.z += p.z; s.w += p.w;
        }
        const float r = rA_s[q];
        s.x *= r; s.y *= r; s.z *= r; s.w *= r;
        *(float4*)(out + (size_t)(b * S1_ + q0 + q) * H_ + lane * 4) = s;
    }
}

extern "C" void kernel_launch(void* const* d_in, const int* in_sizes, int n_in,
                              void* d_out, int out_size, void* d_ws, size_t ws_size,
                              hipStream_t stream) {
    const float* query  = (const float*)d_in[0];  // [16,128,256]
    const float* key    = (const float*)d_in[1];  // [16,256,256]
    const float* value  = (const float*)d_in[2];  // [16,256,256]
    const float* q_mask = (const float*)d_in[3];  // [16,128]
    const float* k_mask = (const float*)d_in[4];  // [16,256]
    const float* W1     = (const float*)d_in[5];  // [512,512]
    const float* b1     = (const float*)d_in[6];  // [512]
    const float* W2     = (const float*)d_in[7];  // [512,1]
    const float* b2     = (const float*)d_in[8];  // [1]
    float*       out    = (float*)d_out;

    _Float16* QPh  = (_Float16*)d_ws;                  // [2048][512]      2 MB
    _Float16* KPTh = QPh  + (size_t)B_ * S1_ * HM_;    // [16][64][256][8] 4 MB
    _Float16* WB   = KPTh + (size_t)B_ * S2_ * HM_;    // frag-order W   0.5 MB

    cvtWB_kernel<<<128, 256, 0, stream>>>(W1, WB);

    proj_mfma_kernel<<<384, 512, 0, stream>>>(query, key, WB, b1, QPh, KPTh);

    attn_kernel<<<dim3(S1_ / QB, B_), 512, 0, stream>>>(
        QPh, KPTh, value, q_mask, k_mask, W2, b2, out);
}